// Round 9
// baseline (70.546 us; speedup 1.0000x reference)
//
#include <hip/hip_runtime.h>
#include <hip/hip_bf16.h>
#include <stdint.h>

#define NGRAPH 64
#define NMAX   512
#define NHEAD  4
#define WPR    (NMAX / 32)                    // 16 bitmap words per row
#define BM_WORDS (NGRAPH * NMAX * WPR)        // 524,288
#define BM_BYTES (BM_WORDS * 4)               // 2 MiB

typedef float f4 __attribute__((ext_vector_type(4)));

// ---------- dispatch A: LDS scan per (graph, 64-row slice) -> dump to global bitmap ----------
#define ROWS_A   64
#define SLICES_A (NMAX / ROWS_A)              // 8
#define NBLK_A   (NGRAPH * SLICES_A)          // 512

__global__ __launch_bounds__(256) void scan_dump_kernel(
    const int* __restrict__ ei,               // [2, E]
    const int* __restrict__ nn,               // [64]
    uint32_t* __restrict__ bm,                // [64][512][16] words
    int E, int epg)
{
    int cpx = NBLK_A >> 3;                    // 64
    int wg  = (blockIdx.x & 7) * cpx + (blockIdx.x >> 3);
    int g     = wg >> 3;
    int slice = wg & 7;
    int r0    = slice * ROWS_A;

    __shared__ uint32_t s_bits[ROWS_A * WPR]; // 4 KB
    __shared__ int s_off;
    int t = threadIdx.x;
#pragma unroll
    for (int z = 0; z < 4; ++z) s_bits[t + z * 256] = 0u;
    if (t < 64) {
        int v = nn[t]; int x = v;
#pragma unroll
        for (int d = 1; d < 64; d <<= 1) { int y = __shfl_up(x, d, 64); if (t >= d) x += y; }
        if (t == g) s_off = x - v;
    }
    __syncthreads();

    int off   = s_off;
    int ebase = g * epg;
    const int4* src4 = reinterpret_cast<const int4*>(ei + ebase);
    int nvec = epg >> 2;
    for (int idx = t; idx < nvec; idx += 256) {
        int4 s = src4[idx];
        int e0 = ebase + (idx << 2);
#pragma unroll
        for (int c = 0; c < 4; ++c) {
            int si = ((const int*)&s)[c] - off;
            unsigned rr = (unsigned)(si - r0);
            if (rr < (unsigned)ROWS_A) {
                int di = ei[E + e0 + c] - off;
                atomicOr(&s_bits[rr * WPR + (di >> 5)], 1u << (di & 31));
            }
        }
    }
    __syncthreads();

    uint4 vd;
    vd.x = s_bits[t * 4 + 0]; vd.y = s_bits[t * 4 + 1];
    vd.z = s_bits[t * 4 + 2]; vd.w = s_bits[t * 4 + 3];
    reinterpret_cast<uint4*>(bm + g * (NMAX * WPR) + r0 * WPR)[t] = vd;
}

// ---------- dispatch B: deep-stream write (fill-mimic v2) ----------
// 512 blocks = (b, h, half). Each wave owns 64 CONSECUTIVE rows (128 KB
// contiguous) of one (b,h) panel and streams them with back-to-back nt
// stores (unroll-4 => 8 stores in flight per thread between loads).
#define WBLK 512
__global__ __launch_bounds__(256) void write_kernel(
    const uint32_t* __restrict__ bm,
    const int* __restrict__ nn,
    const float* __restrict__ W,
    f4* __restrict__ out4)
{
    // same XCD swizzle family: all 8 (h,half) panels of graph b share an XCD
    // so the graph's 32 KB bitmap is HBM-fetched once per XCD.
    int cpx = WBLK >> 3;                      // 64
    int wg  = (blockIdx.x & 7) * cpx + (blockIdx.x >> 3);
    int b = wg >> 3;                          // graph   (wave-uniform)
    int h = (wg >> 1) & 3;                    // head    (wave-uniform)
    int s = wg & 1;                           // row half
    int t = threadIdx.x;
    int lane = t & 63;
    int wv   = t >> 6;                        // wave in block: 0..3
    int i0   = s * 256 + wv * 64;             // first row owned by this wave

    int nb = nn[b];
    float w0 = W[h], w1 = W[4 + h], w6 = W[24 + h];

    int wq = lane >> 3;
    int sh = (lane & 7) << 2;
    int j0 = lane << 2;

    const uint32_t* bmg = bm + (b << 13);     // graph bitmap base (512*16 words)
    size_t obase = ((size_t)((b * 4 + h) << 9) + (size_t)i0) << 7;  // row*128 f4

#pragma unroll 4
    for (int rr = 0; rr < 64; ++rr) {
        int i = i0 + rr;
        uint32_t blo = bmg[i * WPR + wq]     >> sh;
        uint32_t bhi = bmg[i * WPR + 8 + wq] >> sh;
        f4 lo, hi;
        bool dv = (i < nb);
#pragma unroll
        for (int k = 0; k < 4; ++k) {
            float v = ((blo >> k) & 1u) ? w1 : w6;
            if (dv && (j0 + k) == i) v = w0;
            lo[k] = v;
            float v2 = ((bhi >> k) & 1u) ? w1 : w6;
            if (dv && (256 + j0 + k) == i) v2 = w0;
            hi[k] = v2;
        }
        __builtin_nontemporal_store(lo, &out4[obase + (size_t)rr * 128 + lane]);
        __builtin_nontemporal_store(hi, &out4[obase + (size_t)rr * 128 + 64 + lane]);
    }
}

// ---------- fallback (ws too small): R6 fused kernel ----------
#define ROWS_PER_BLOCK 64
#define SLICES (NMAX / ROWS_PER_BLOCK)
#define NBLOCKS (NGRAPH * SLICES)

__global__ __launch_bounds__(256) void fused_structenc_kernel(
    const int* __restrict__ ei, const int* __restrict__ nn,
    const float* __restrict__ W, f4* __restrict__ out4, int E, int epg)
{
    int cpx = NBLOCKS >> 3;
    int wg  = (blockIdx.x & 7) * cpx + (blockIdx.x >> 3);
    int g     = wg >> 3;
    int slice = wg & 7;
    int r0    = slice * ROWS_PER_BLOCK;
    __shared__ uint32_t s_bits[ROWS_PER_BLOCK * WPR];
    __shared__ int s_off;
    int t = threadIdx.x;
#pragma unroll
    for (int z = 0; z < 4; ++z) s_bits[t + z * 256] = 0u;
    if (t < 64) {
        int v = nn[t]; int x = v;
#pragma unroll
        for (int d = 1; d < 64; d <<= 1) { int y = __shfl_up(x, d, 64); if (t >= d) x += y; }
        if (t == g) s_off = x - v;
    }
    __syncthreads();
    int off = s_off;
    int ebase = g * epg;
    const int4* src4 = reinterpret_cast<const int4*>(ei + ebase);
    int nvec = epg >> 2;
    for (int idx = t; idx < nvec; idx += 256) {
        int4 s = src4[idx];
        int e0 = ebase + (idx << 2);
#pragma unroll
        for (int c = 0; c < 4; ++c) {
            int si = ((const int*)&s)[c] - off;
            unsigned rr = (unsigned)(si - r0);
            if (rr < (unsigned)ROWS_PER_BLOCK) {
                int di = ei[E + e0 + c] - off;
                atomicOr(&s_bits[rr * WPR + (di >> 5)], 1u << (di & 31));
            }
        }
    }
    __syncthreads();
    int lane = t & 63;
    int h    = t >> 6;
    int nb   = nn[g];
    float w0 = W[h], w1 = W[4 + h], w6 = W[24 + h];
    size_t outbase = ((size_t)(g * NHEAD + h) * NMAX + r0) * (NMAX / 4);
    int j0 = lane << 2;
#pragma unroll 8
    for (int r = 0; r < ROWS_PER_BLOCK; ++r) {
        int i = r0 + r;
        uint32_t blo = s_bits[r * WPR +     (lane >> 3)] >> ((lane & 7) << 2);
        uint32_t bhi = s_bits[r * WPR + 8 + (lane >> 3)] >> ((lane & 7) << 2);
        f4 lo, hi;
        bool dv = (i < nb);
#pragma unroll
        for (int k2 = 0; k2 < 4; ++k2) {
            float v = ((blo >> k2) & 1u) ? w1 : w6;
            if (dv && (j0 + k2) == i) v = w0;
            lo[k2] = v;
            float v2 = ((bhi >> k2) & 1u) ? w1 : w6;
            if (dv && (256 + j0 + k2) == i) v2 = w0;
            hi[k2] = v2;
        }
        __builtin_nontemporal_store(lo, &out4[outbase + (size_t)r * 128 + lane]);
        __builtin_nontemporal_store(hi, &out4[outbase + (size_t)r * 128 + 64 + lane]);
    }
}

extern "C" void kernel_launch(void* const* d_in, const int* in_sizes, int n_in,
                              void* d_out, int out_size, void* d_ws, size_t ws_size,
                              hipStream_t stream) {
    const int*   ei = (const int*)d_in[0];
    const int*   nn = (const int*)d_in[2];
    const float* W  = (const float*)d_in[3];
    f4* out4 = (f4*)d_out;

    int E   = in_sizes[0] / 2;       // 1,048,576
    int epg = E / NGRAPH;            // 16,384

    if (ws_size >= (size_t)BM_BYTES) {
        uint32_t* bm = (uint32_t*)d_ws;
        scan_dump_kernel<<<NBLK_A, 256, 0, stream>>>(ei, nn, bm, E, epg);
        write_kernel<<<WBLK, 256, 0, stream>>>(bm, nn, W, out4);
    } else {
        fused_structenc_kernel<<<NBLOCKS, 256, 0, stream>>>(ei, nn, W, out4, E, epg);
    }
}

// Round 10
// 69.719 us; speedup vs baseline: 1.0119x; 1.0119x over previous
//
#include <hip/hip_runtime.h>
#include <hip/hip_bf16.h>
#include <stdint.h>

#define NGRAPH 64
#define NMAX   512
#define NHEAD  4
#define WPR    (NMAX / 32)                    // 16 bitmap words per row
#define BM_WORDS (NGRAPH * NMAX * WPR)        // 524,288
#define BM_BYTES (BM_WORDS * 4)               // 2 MiB

typedef float f4 __attribute__((ext_vector_type(4)));

// ---------- dispatch A: LDS scan per (graph, 64-row slice) -> dump to global bitmap ----------
#define ROWS_A   64
#define SLICES_A (NMAX / ROWS_A)              // 8
#define NBLK_A   (NGRAPH * SLICES_A)          // 512

__global__ __launch_bounds__(256) void scan_dump_kernel(
    const int* __restrict__ ei,               // [2, E]
    const int* __restrict__ nn,               // [64]
    uint32_t* __restrict__ bm,                // [64][512][16] words
    int E, int epg)
{
    int cpx = NBLK_A >> 3;                    // 64
    int wg  = (blockIdx.x & 7) * cpx + (blockIdx.x >> 3);
    int g     = wg >> 3;
    int slice = wg & 7;
    int r0    = slice * ROWS_A;

    __shared__ uint32_t s_bits[ROWS_A * WPR]; // 4 KB
    __shared__ int s_off;
    int t = threadIdx.x;
#pragma unroll
    for (int z = 0; z < 4; ++z) s_bits[t + z * 256] = 0u;
    if (t < 64) {
        int v = nn[t]; int x = v;
#pragma unroll
        for (int d = 1; d < 64; d <<= 1) { int y = __shfl_up(x, d, 64); if (t >= d) x += y; }
        if (t == g) s_off = x - v;
    }
    __syncthreads();

    int off   = s_off;
    int ebase = g * epg;
    const int4* src4 = reinterpret_cast<const int4*>(ei + ebase);
    int nvec = epg >> 2;
    for (int idx = t; idx < nvec; idx += 256) {
        int4 s = src4[idx];
        int e0 = ebase + (idx << 2);
#pragma unroll
        for (int c = 0; c < 4; ++c) {
            int si = ((const int*)&s)[c] - off;
            unsigned rr = (unsigned)(si - r0);
            if (rr < (unsigned)ROWS_A) {
                int di = ei[E + e0 + c] - off;
                atomicOr(&s_bits[rr * WPR + (di >> 5)], 1u << (di & 31));
            }
        }
    }
    __syncthreads();

    uint4 vd;
    vd.x = s_bits[t * 4 + 0]; vd.y = s_bits[t * 4 + 1];
    vd.z = s_bits[t * 4 + 2]; vd.w = s_bits[t * 4 + 3];
    reinterpret_cast<uint4*>(bm + g * (NMAX * WPR) + r0 * WPR)[t] = vd;
}

// ---------- dispatch B: software-pipelined write ----------
// 4096 blocks x 4 waves = 16,384 waves (same TLP as R8). Each wave owns 8
// consecutive rows of one (b,h) panel. Bits for row r+1 are loaded BEFORE
// row r's stores issue, so the nt-store stream never waits on a load.
#define WBLK 4096
__global__ __launch_bounds__(256) void write_kernel(
    const uint32_t* __restrict__ bm,
    const int* __restrict__ nn,
    const float* __restrict__ W,
    f4* __restrict__ out4)
{
    int t    = threadIdx.x;
    int lane = t & 63;
    int wg   = blockIdx.x * 4 + (t >> 6);     // global wave id, 16384 total
    int R0   = wg << 3;                       // first of 8 consecutive rows
    int i0   = R0 & 511;                      // wave-uniform
    int h    = (R0 >> 9) & 3;                 // wave-uniform
    int b    = R0 >> 11;                      // wave-uniform

    int nb = nn[b];
    float w0 = W[h], w1 = W[4 + h], w6 = W[24 + h];

    int wq = lane >> 3;
    int sh = (lane & 7) << 2;
    int j0 = lane << 2;

    const uint32_t* rowp = bm + ((b << 9) + i0) * WPR;
    size_t obase = (size_t)R0 << 7;           // row * 128 f4

    // prologue: load row 0's bits
    uint32_t nlo = rowp[wq] >> sh;
    uint32_t nhi = rowp[8 + wq] >> sh;

#pragma unroll
    for (int r = 0; r < 8; ++r) {
        uint32_t blo = nlo, bhi = nhi;
        if (r < 7) {                          // issue next row's loads early
            nlo = rowp[(r + 1) * WPR + wq] >> sh;
            nhi = rowp[(r + 1) * WPR + 8 + wq] >> sh;
        }
        int i = i0 + r;
        bool dv = (i < nb);
        f4 lo, hi;
#pragma unroll
        for (int k = 0; k < 4; ++k) {
            float v = ((blo >> k) & 1u) ? w1 : w6;
            if (dv && (j0 + k) == i) v = w0;
            lo[k] = v;
            float v2 = ((bhi >> k) & 1u) ? w1 : w6;
            if (dv && (256 + j0 + k) == i) v2 = w0;
            hi[k] = v2;
        }
        __builtin_nontemporal_store(lo, &out4[obase + (size_t)r * 128 + lane]);
        __builtin_nontemporal_store(hi, &out4[obase + (size_t)r * 128 + 64 + lane]);
    }
}

// ---------- fallback (ws too small): R6 fused kernel ----------
#define ROWS_PER_BLOCK 64
#define SLICES (NMAX / ROWS_PER_BLOCK)
#define NBLOCKS (NGRAPH * SLICES)

__global__ __launch_bounds__(256) void fused_structenc_kernel(
    const int* __restrict__ ei, const int* __restrict__ nn,
    const float* __restrict__ W, f4* __restrict__ out4, int E, int epg)
{
    int cpx = NBLOCKS >> 3;
    int wg  = (blockIdx.x & 7) * cpx + (blockIdx.x >> 3);
    int g     = wg >> 3;
    int slice = wg & 7;
    int r0    = slice * ROWS_PER_BLOCK;
    __shared__ uint32_t s_bits[ROWS_PER_BLOCK * WPR];
    __shared__ int s_off;
    int t = threadIdx.x;
#pragma unroll
    for (int z = 0; z < 4; ++z) s_bits[t + z * 256] = 0u;
    if (t < 64) {
        int v = nn[t]; int x = v;
#pragma unroll
        for (int d = 1; d < 64; d <<= 1) { int y = __shfl_up(x, d, 64); if (t >= d) x += y; }
        if (t == g) s_off = x - v;
    }
    __syncthreads();
    int off = s_off;
    int ebase = g * epg;
    const int4* src4 = reinterpret_cast<const int4*>(ei + ebase);
    int nvec = epg >> 2;
    for (int idx = t; idx < nvec; idx += 256) {
        int4 s = src4[idx];
        int e0 = ebase + (idx << 2);
#pragma unroll
        for (int c = 0; c < 4; ++c) {
            int si = ((const int*)&s)[c] - off;
            unsigned rr = (unsigned)(si - r0);
            if (rr < (unsigned)ROWS_PER_BLOCK) {
                int di = ei[E + e0 + c] - off;
                atomicOr(&s_bits[rr * WPR + (di >> 5)], 1u << (di & 31));
            }
        }
    }
    __syncthreads();
    int lane = t & 63;
    int h    = t >> 6;
    int nb   = nn[g];
    float w0 = W[h], w1 = W[4 + h], w6 = W[24 + h];
    size_t outbase = ((size_t)(g * NHEAD + h) * NMAX + r0) * (NMAX / 4);
    int j0 = lane << 2;
#pragma unroll 8
    for (int r = 0; r < ROWS_PER_BLOCK; ++r) {
        int i = r0 + r;
        uint32_t blo = s_bits[r * WPR +     (lane >> 3)] >> ((lane & 7) << 2);
        uint32_t bhi = s_bits[r * WPR + 8 + (lane >> 3)] >> ((lane & 7) << 2);
        f4 lo, hi;
        bool dv = (i < nb);
#pragma unroll
        for (int k2 = 0; k2 < 4; ++k2) {
            float v = ((blo >> k2) & 1u) ? w1 : w6;
            if (dv && (j0 + k2) == i) v = w0;
            lo[k2] = v;
            float v2 = ((bhi >> k2) & 1u) ? w1 : w6;
            if (dv && (256 + j0 + k2) == i) v2 = w0;
            hi[k2] = v2;
        }
        __builtin_nontemporal_store(lo, &out4[outbase + (size_t)r * 128 + lane]);
        __builtin_nontemporal_store(hi, &out4[outbase + (size_t)r * 128 + 64 + lane]);
    }
}

extern "C" void kernel_launch(void* const* d_in, const int* in_sizes, int n_in,
                              void* d_out, int out_size, void* d_ws, size_t ws_size,
                              hipStream_t stream) {
    const int*   ei = (const int*)d_in[0];
    const int*   nn = (const int*)d_in[2];
    const float* W  = (const float*)d_in[3];
    f4* out4 = (f4*)d_out;

    int E   = in_sizes[0] / 2;       // 1,048,576
    int epg = E / NGRAPH;            // 16,384

    if (ws_size >= (size_t)BM_BYTES) {
        uint32_t* bm = (uint32_t*)d_ws;
        scan_dump_kernel<<<NBLK_A, 256, 0, stream>>>(ei, nn, bm, E, epg);
        write_kernel<<<WBLK, 256, 0, stream>>>(bm, nn, W, out4);
    } else {
        fused_structenc_kernel<<<NBLOCKS, 256, 0, stream>>>(ei, nn, W, out4, E, epg);
    }
}

// Round 11
// 62.843 us; speedup vs baseline: 1.1226x; 1.1094x over previous
//
#include <hip/hip_runtime.h>
#include <hip/hip_bf16.h>
#include <stdint.h>

#define NGRAPH 64
#define NMAX   512
#define NHEAD  4
#define ROWS_PER_BLOCK 64
#define SLICES (NMAX / ROWS_PER_BLOCK)            // 8 slices per graph
#define NBLOCKS (NGRAPH * SLICES)                 // 512 blocks

typedef float f4 __attribute__((ext_vector_type(4)));

// FINAL (revert to R6, best measured: 62.8 us).
// Single fused kernel. Block = (graph g, 64-row slice).
// - LDS adjacency bitmap per slice (no global atomics, no extra dispatches)
// - nontemporal f4 stores: L2 write-allocate bypass (98 -> 63 us, the one
//   structural win; value-computing nt-store streams cap at ~5.2 TB/s vs
//   7.0 TB/s pure-fill — confirmed across 4 write-shape variants R6/R8/R9/R10)
// - XCD swizzle: 8 slices of a graph share an XCD -> edge list L2-hit
__global__ __launch_bounds__(256) void fused_structenc_kernel(
    const int* __restrict__ ei,      // [2, E] (src row, then dst row)
    const int* __restrict__ nn,      // [64]
    const float* __restrict__ W,     // [7, 4]
    f4* __restrict__ out4,           // [64,4,512,512] as float4
    int E, int epg)
{
    int cpx = NBLOCKS >> 3;                        // 64
    int wg  = (blockIdx.x & 7) * cpx + (blockIdx.x >> 3);
    int g     = wg >> 3;                           // graph id (wave-uniform)
    int slice = wg & 7;
    int r0    = slice * ROWS_PER_BLOCK;

    __shared__ uint32_t s_bits[ROWS_PER_BLOCK * (NMAX / 32)];  // 4 KB
    __shared__ int s_off;

    int t = threadIdx.x;
#pragma unroll
    for (int z = 0; z < 4; ++z) s_bits[t + z * 256] = 0u;

    if (t < 64) {
        int v = nn[t];
        int x = v;
#pragma unroll
        for (int d = 1; d < 64; d <<= 1) {
            int y = __shfl_up(x, d, 64);
            if (t >= d) x += y;
        }
        if (t == g) s_off = x - v;
    }
    __syncthreads();

    int off   = s_off;
    int ebase = g * epg;
    const int4* src4 = reinterpret_cast<const int4*>(ei + ebase);
    int nvec = epg >> 2;                           // 4096
    for (int idx = t; idx < nvec; idx += 256) {
        int4 s = src4[idx];
        int e0 = ebase + (idx << 2);
#pragma unroll
        for (int c = 0; c < 4; ++c) {
            int si = ((const int*)&s)[c] - off;
            unsigned rr = (unsigned)(si - r0);
            if (rr < (unsigned)ROWS_PER_BLOCK) {
                int di = ei[E + e0 + c] - off;
                atomicOr(&s_bits[rr * 16 + (di >> 5)], 1u << (di & 31));
            }
        }
    }
    // tail (epg not multiple of 1024) — no-op for this problem size
    for (int k = (nvec << 2) + t; k < epg; k += 256) {
        int si = ei[ebase + k] - off;
        unsigned rr = (unsigned)(si - r0);
        if (rr < (unsigned)ROWS_PER_BLOCK) {
            int di = ei[E + ebase + k] - off;
            atomicOr(&s_bits[rr * 16 + (di >> 5)], 1u << (di & 31));
        }
    }
    __syncthreads();

    // write phase: wave = head; 64 rows x 2 KB/row, nt stores
    int lane = t & 63;
    int h    = t >> 6;
    int nb   = nn[g];                              // scalar (g uniform)
    float w0 = W[h];                               // dist 0 (diagonal)
    float w1 = W[4 + h];                           // dist 1 (edge)
    float w6 = W[24 + h];                          // dist K+1 (default)
    size_t outbase = ((size_t)(g * NHEAD + h) * NMAX + r0) * (NMAX / 4);

    int j0 = lane << 2;
#pragma unroll 8
    for (int r = 0; r < ROWS_PER_BLOCK; ++r) {
        int i = r0 + r;
        uint32_t blo = s_bits[r * 16 +     (lane >> 3)] >> ((lane & 7) << 2);
        uint32_t bhi = s_bits[r * 16 + 8 + (lane >> 3)] >> ((lane & 7) << 2);
        f4 lo, hi;
        bool dv = (i < nb);
#pragma unroll
        for (int k2 = 0; k2 < 4; ++k2) {
            float v = ((blo >> k2) & 1u) ? w1 : w6;
            if (dv && (j0 + k2) == i) v = w0;
            lo[k2] = v;
            float v2 = ((bhi >> k2) & 1u) ? w1 : w6;
            if (dv && (256 + j0 + k2) == i) v2 = w0;
            hi[k2] = v2;
        }
        __builtin_nontemporal_store(lo, &out4[outbase + (size_t)r * 128 + lane]);
        __builtin_nontemporal_store(hi, &out4[outbase + (size_t)r * 128 + 64 + lane]);
    }
}

extern "C" void kernel_launch(void* const* d_in, const int* in_sizes, int n_in,
                              void* d_out, int out_size, void* d_ws, size_t ws_size,
                              hipStream_t stream) {
    const int*   ei = (const int*)d_in[0];
    const int*   nn = (const int*)d_in[2];
    const float* W  = (const float*)d_in[3];
    f4* out4 = (f4*)d_out;

    int E   = in_sizes[0] / 2;       // 1,048,576
    int epg = E / NGRAPH;            // 16,384

    fused_structenc_kernel<<<NBLOCKS, 256, 0, stream>>>(ei, nn, W, out4, E, epg);
}